// Round 8
// baseline (9441.997 us; speedup 1.0000x reference)
//
#include <hip/hip_runtime.h>
#include <hip/hip_bf16.h>
#include <hip/hip_fp16.h>
#include <cstddef>

// GRU (Keras reset_after=True), persistent kernel, FLAGLESS tagged comm.
//   64 WGs (1/CU), WG w owns hidden [16w,16w+16) -> 48 gate cols.
//   Wave mt handles batches [16mt,16mt+16).
//   comm element = dword (tag16<<16 | h_fp16): self-validating; all-to-all
//   dependency bounds skew <=1 so 2-parity buffering needs NO flags, NO
//   producer drain. Consumer: probe-spin (1 dword per producer) -> bulk
//   tagged load -> per-chunk pack(v_perm)+min-validate+speculative MFMA,
//   wholesale retry on stale. wz/wr in regs(AGPR), wh in LDS (R4 structure).
//   R8 fix: R7's probe pointer wrongly included the consumer's l*8 offset ->
//   lane63/plane3 probed the opposite-parity region (tags never match) ->
//   deterministic spin hang. Probe base now built without l*8.

#define VOCABN 128
#define HIDN   1024
#define BN     64
#define TN     1024
#define C3N    3072
#define NWG    64
#define NREP   2

typedef _Float16 half8 __attribute__((ext_vector_type(8)));
typedef float    f32x4 __attribute__((ext_vector_type(4)));
typedef unsigned int u32x4 __attribute__((ext_vector_type(4)));

// ---------------- Mtab (fp16): M[v][c] = sum_e emb[v][e]*w_in[e][c] + b_in[c]
__global__ __launch_bounds__(256, 1) void emb_gemm(
    const float* __restrict__ emb, const float* __restrict__ w_in,
    const float* __restrict__ b_in, _Float16* __restrict__ Mtab)
{
    __shared__ float se[16][256];
    const int tid = threadIdx.x;
    const int c   = blockIdx.x * 256 + tid;   // 12 x
    const int v0  = blockIdx.y * 16;          // 8 y
#pragma unroll
    for (int i = 0; i < 16; ++i) {
        int flat = i * 256 + tid;
        int r = flat >> 8, e = flat & 255;
        se[r][e] = emb[(v0 + r) * 256 + e];
    }
    __syncthreads();
    float acc[16];
#pragma unroll
    for (int r = 0; r < 16; ++r) acc[r] = 0.f;
    for (int e = 0; e < 256; ++e) {
        float w = w_in[(size_t)e * C3N + c];
#pragma unroll
        for (int r = 0; r < 16; ++r) acc[r] = fmaf(se[r][e], w, acc[r]);
    }
    float bc = b_in[c];
#pragma unroll
    for (int r = 0; r < 16; ++r)
        Mtab[(size_t)(v0 + r) * C3N + c] = (_Float16)(acc[r] + bc);
}

// ---------------- persistent GRU over all T ---------------------------------
// comm layout (dwords): [rep][parity][plane mt][16384], rep stride 131072.
__global__ __launch_bounds__(256, 1) void gru_persist(
    const int* __restrict__ ids, const _Float16* __restrict__ Mtab_g,
    const float* __restrict__ w_rec, const float* __restrict__ b_rec,
    unsigned int* __restrict__ comm,    // NREP * 2 * 65536 dwords (1 MB)
    _Float16* __restrict__ hs)          // [T][B][H] fp16
{
    __shared__ _Float16 wh[32 * 64 * 8];      // 32 KB, B-frags [kt][lane][8]
    __shared__ _Float16 mtab[VOCABN * 48];    // 12 KB
    const half8* whp = (const half8*)wh;

    const int tid = threadIdx.x;
    const int w   = blockIdx.x;           // 0..63
    const int mt  = tid >> 6;
    const int l   = tid & 63;
    const int jj  = l & 15;
    const int lh  = l >> 4;

    // ---- LDS init: W_h in B-frag order ----------------------------------
    for (int i = 0; i < 64; ++i) {
        int flat = i * 256 + tid;                       // 16384 = 32*64*8
        int e  = flat & 7;
        int ll = (flat >> 3) & 63;
        int kt = flat >> 9;
        int k   = kt * 32 + (ll >> 4) * 8 + e;
        int col = 2048 + w * 16 + (ll & 15);
        wh[(kt * 64 + ll) * 8 + e] = (_Float16)w_rec[(size_t)k * C3N + col];
    }
    for (int i = 0; i < 24; ++i) {
        int flat = i * 256 + tid;                       // 6144 = 128*48
        int v = flat / 48, c = flat % 48;
        int col = (c >> 4) * 1024 + w * 16 + (c & 15);
        mtab[v * 48 + c] = Mtab_g[(size_t)v * C3N + col];
    }
    // ---- register(AGPR)-resident weights: z and r gates ------------------
    half8 wz[32], wr[32];
#pragma unroll
    for (int kt = 0; kt < 32; ++kt) {
#pragma unroll
        for (int e = 0; e < 8; ++e) {
            int k = kt * 32 + lh * 8 + e;
            wz[kt][e] = (_Float16)w_rec[(size_t)k * C3N + w * 16 + jj];
            wr[kt][e] = (_Float16)w_rec[(size_t)k * C3N + 1024 + w * 16 + jj];
        }
    }
    const float bz = b_rec[w * 16 + jj];
    const float br = b_rec[1024 + w * 16 + jj];
    const float bh = b_rec[2048 + w * 16 + jj];
    __syncthreads();                                    // last barrier

    const int bbase = mt * 16 + lh * 4;
    float hprev[4] = {0.f, 0.f, 0.f, 0.f};

    const int ktp = w >> 1;
    const int lp  = 16 * ((w & 1) * 2 + (jj >> 3));
    unsigned int* cw_base = comm + (size_t)mt * 16384 + ktp * 512 + lp * 8 + (jj & 7);
    // plane base for this consumer (NO lane offset) + lane offset separately
    const unsigned int* plane_base = comm + (size_t)(w & 1) * 131072
                                   + (size_t)mt * 16384;
    const unsigned int* cr_base = plane_base + (size_t)l * 8;

    int idsv[4];
#pragma unroll
    for (int q = 0; q < 4; ++q) idsv[q] = ids[(size_t)(bbase + q) * TN];

#define ISSUE(BUF, C) do { _Pragma("unroll")                                  \
    for (int u_ = 0; u_ < 4; ++u_) {                                          \
        asm volatile("global_load_dwordx4 %0, %1, off sc0 sc1"                \
            : "=v"(BUF[2*u_])   : "v"(crd + (4*(C)+u_)*512)     : "memory");  \
        asm volatile("global_load_dwordx4 %0, %1, off sc0 sc1"                \
            : "=v"(BUF[2*u_+1]) : "v"(crd + (4*(C)+u_)*512 + 4) : "memory");  \
    } } while (0)

#define WAITN(N) do {                                                         \
    asm volatile("s_waitcnt vmcnt(" #N ")" ::: "memory");                     \
    __builtin_amdgcn_sched_barrier(0); } while (0)

#define PROC(BUF, C) do { _Pragma("unroll")                                   \
    for (int u_ = 0; u_ < 4; ++u_) {                                          \
        u32x4 lo_ = BUF[2*u_], hi_ = BUF[2*u_+1];                             \
        minv = lo_[0] < minv ? lo_[0] : minv;                                 \
        minv = lo_[1] < minv ? lo_[1] : minv;                                 \
        minv = lo_[2] < minv ? lo_[2] : minv;                                 \
        minv = lo_[3] < minv ? lo_[3] : minv;                                 \
        minv = hi_[0] < minv ? hi_[0] : minv;                                 \
        minv = hi_[1] < minv ? hi_[1] : minv;                                 \
        minv = hi_[2] < minv ? hi_[2] : minv;                                 \
        minv = hi_[3] < minv ? hi_[3] : minv;                                 \
        u32x4 fr_;                                                            \
        fr_[0] = __builtin_amdgcn_perm(lo_[1], lo_[0], 0x05040100u);          \
        fr_[1] = __builtin_amdgcn_perm(lo_[3], lo_[2], 0x05040100u);          \
        fr_[2] = __builtin_amdgcn_perm(hi_[1], hi_[0], 0x05040100u);          \
        fr_[3] = __builtin_amdgcn_perm(hi_[3], hi_[2], 0x05040100u);          \
        half8 a_ = __builtin_bit_cast(half8, fr_);                            \
        acc0 = __builtin_amdgcn_mfma_f32_16x16x32_f16(a_, wz[4*(C)+u_], acc0, 0, 0, 0); \
        acc1 = __builtin_amdgcn_mfma_f32_16x16x32_f16(a_, wr[4*(C)+u_], acc1, 0, 0, 0); \
        acc2 = __builtin_amdgcn_mfma_f32_16x16x32_f16(a_, whp[(4*(C)+u_)*64 + l], acc2, 0, 0, 0); \
    } } while (0)

    for (int t = 0; t < TN; ++t) {
        f32x4 acc0 = {0.f, 0.f, 0.f, 0.f};
        f32x4 acc1 = {0.f, 0.f, 0.f, 0.f};
        f32x4 acc2 = {0.f, 0.f, 0.f, 0.f};

        if (t > 0) {
            const unsigned int tg = (unsigned int)t;
            const unsigned int* crd = cr_base + (size_t)(t & 1) * 65536;
            // probe slot of producer w=l: chunk l>>1, half (l&1) -- from
            // plane_base (R8 fix: no stray l*8 term)
            const unsigned int* prp = plane_base + (size_t)(t & 1) * 65536
                                    + (l >> 1) * 512 + (l & 1) * 256;
            // ---- probe spin: one dword per producer WG (64 lanes) --------
            while (true) {
                unsigned int p;
                asm volatile("global_load_dword %0, %1, off sc0 sc1\n\t"
                             "s_waitcnt vmcnt(0)"
                             : "=v"(p) : "v"(prp) : "memory");
                if (__all((p >> 16) == tg)) break;
                __builtin_amdgcn_s_sleep(1);
            }
            __builtin_amdgcn_sched_barrier(0);
            // ---- bulk tagged load + validate + speculative MFMA ----------
            u32x4 bufA[8], bufB[8], bufC[8], bufD[8];
            for (;;) {
                acc0 = f32x4{0.f, 0.f, 0.f, 0.f};
                acc1 = f32x4{0.f, 0.f, 0.f, 0.f};
                acc2 = f32x4{0.f, 0.f, 0.f, 0.f};
                unsigned int minv = 0xFFFFFFFFu;
                ISSUE(bufA, 0); ISSUE(bufB, 1); ISSUE(bufC, 2); ISSUE(bufD, 3);
                WAITN(24); PROC(bufA, 0);
                if (!__all((minv >> 16) == tg)) {           // early stale exit
                    __builtin_amdgcn_s_sleep(1);
                    continue;
                }
                ISSUE(bufA, 4);
                WAITN(24); PROC(bufB, 1); ISSUE(bufB, 5);
                WAITN(24); PROC(bufC, 2); ISSUE(bufC, 6);
                WAITN(24); PROC(bufD, 3); ISSUE(bufD, 7);
                WAITN(24); PROC(bufA, 4);
                WAITN(16); PROC(bufB, 5);
                WAITN(8);  PROC(bufC, 6);
                WAITN(0);  PROC(bufD, 7);
                if (__all((minv >> 16) == tg)) break;       // full validation
                __builtin_amdgcn_s_sleep(1);
            }
        }

        // ---- gates (C layout: col=lane&15, row=(lane>>4)*4+q) ------------
        float hnv[4];
#pragma unroll
        for (int q = 0; q < 4; ++q) {
            float az = acc0[q], ar = acc1[q], ah = acc2[q];
            int id = idsv[q];
            float xz = (float)mtab[id * 48 + jj];
            float xr = (float)mtab[id * 48 + 16 + jj];
            float xh = (float)mtab[id * 48 + 32 + jj];
            float z  = 1.f / (1.f + __expf(-(xz + az + bz)));
            float r  = 1.f / (1.f + __expf(-(xr + ar + br)));
            float hh = tanhf(xh + r * (ah + bh));
            float hn = z * hprev[q] + (1.f - z) * hh;
            hprev[q] = hn;
            hnv[q] = hn;
        }
        // ---- publish h_{t+1}: tagged dwords, fire-and-forget -------------
        const unsigned int tagp = (unsigned int)(t + 1) << 16;
        unsigned int* cwp = cw_base + (size_t)((t + 1) & 1) * 65536;
#pragma unroll
        for (int q = 0; q < 4; ++q) {
            unsigned int hv = tagp | (unsigned int)__builtin_bit_cast(
                unsigned short, (_Float16)hnv[q]);
#pragma unroll
            for (int rr = 0; rr < NREP; ++rr)
                asm volatile("global_store_dword %0, %1, off sc0 sc1"
                             :: "v"(cwp + rr * 131072 + (lh * 4 + q) * 8),
                                "v"(hv) : "memory");
        }
        // hs stores (plain cached) + ids prefetch
#pragma unroll
        for (int q = 0; q < 4; ++q)
            hs[((size_t)t * BN + (bbase + q)) * HIDN + w * 16 + jj] = (_Float16)hnv[q];
        if (t + 1 < TN) {
#pragma unroll
            for (int q = 0; q < 4; ++q)
                idsv[q] = ids[(size_t)(bbase + q) * TN + t + 1];
        }
    }
#undef ISSUE
#undef WAITN
#undef PROC
}

// ---------------- logits: hs[T*B,H] fp16 @ w_out + b_out --------------------
__global__ __launch_bounds__(256, 2) void out_gemm(
    const _Float16* __restrict__ hs, const float* __restrict__ w_out,
    const float* __restrict__ b_out, float* __restrict__ out)
{
    __shared__ float sa[16][1024];
    const int tid = threadIdx.x;
    const int m0  = blockIdx.x * 16;
#pragma unroll
    for (int i = 0; i < 8; ++i) {
        int flat = i * 256 + tid;
        int r = flat >> 7, kc = flat & 127;
        half8 hv = *(const half8*)(hs + (size_t)(m0 + r) * 1024 + kc * 8);
#pragma unroll
        for (int e = 0; e < 8; ++e) sa[r][kc * 8 + e] = (float)hv[e];
    }
    __syncthreads();
    const int v = tid & 127, g = tid >> 7;
    float acc[8];
#pragma unroll
    for (int r = 0; r < 8; ++r) acc[r] = 0.f;
    for (int k = 0; k < 1024; ++k) {
        float wv = w_out[(size_t)k * VOCABN + v];
#pragma unroll
        for (int r = 0; r < 8; ++r) acc[r] = fmaf(sa[g * 8 + r][k], wv, acc[r]);
    }
    float bo = b_out[v];
#pragma unroll
    for (int r = 0; r < 8; ++r) {
        int m = m0 + g * 8 + r;
        out[((size_t)(m & 63) * TN + (m >> 6)) * VOCABN + v] = acc[r] + bo;
    }
}

extern "C" void kernel_launch(void* const* d_in, const int* in_sizes, int n_in,
                              void* d_out, int out_size, void* d_ws, size_t ws_size,
                              hipStream_t stream) {
    const int*   ids   = (const int*)d_in[0];
    const float* emb   = (const float*)d_in[1];
    const float* w_in  = (const float*)d_in[2];
    const float* b_in  = (const float*)d_in[3];
    const float* w_rec = (const float*)d_in[4];
    const float* b_rec = (const float*)d_in[5];
    const float* w_out = (const float*)d_in[6];
    const float* b_out = (const float*)d_in[7];
    float* out = (float*)d_out;

    char* ws = (char*)d_ws;
    _Float16* Mtab = (_Float16*)ws;                        // 768 KB (fp16)
    size_t off = (size_t)VOCABN * C3N * 2;
    unsigned int* comm = (unsigned int*)(ws + off);
    off += (size_t)NREP * 2 * 65536 * 4;                   // 1 MB
    _Float16* hs = (_Float16*)(ws + off);                  // 128 MB

    emb_gemm<<<dim3(12, 8), 256, 0, stream>>>(emb, w_in, b_in, Mtab);
    hipMemsetAsync(comm, 0, (size_t)NREP * 2 * 65536 * 4, stream);

    gru_persist<<<NWG, 256, 0, stream>>>(ids, Mtab, w_rec, b_rec, comm, hs);
    out_gemm<<<(BN * TN) / 16, 256, 0, stream>>>(hs, w_out, b_out, out);
}

// Round 9
// 9179.088 us; speedup vs baseline: 1.0286x; 1.0286x over previous
//
#include <hip/hip_runtime.h>
#include <hip/hip_bf16.h>
#include <hip/hip_fp16.h>
#include <cstddef>

// GRU (Keras reset_after=True), persistent kernel, FLAGLESS tagged comm v2.
//   64 WGs (1/CU), WG w owns hidden [16w,16w+16) -> 48 gate cols.
//   Wave mt handles batches [16mt,16mt+16).
//   comm element = dword (tag16<<16 | h_fp16). Fire-and-forget publish (no
//   drain, no flag: saves ~2 LLC hops/step vs R6 flag protocol).
//   R9 fixes vs R8 (9.0ms, retry storms):
//    - probe the producer's LAST-issued slot (q=3, +24 dwords), not the
//      first: when it's visible the rest of the wave's stores almost
//      certainly are -> first-pass staleness is rare.
//    - per-chunk inline retry (reload 2 dwordx4 of the stale chunk only),
//      not whole-buffer restart. Chunk ids stay compile-time constants so
//      wz/wr stay register(AGPR)-resident. Ladder self-heals after the
//      retry's vmcnt(0) (later counted waits degrade to no-ops safely).

#define VOCABN 128
#define HIDN   1024
#define BN     64
#define TN     1024
#define C3N    3072
#define NWG    64
#define NREP   2

typedef _Float16 half8 __attribute__((ext_vector_type(8)));
typedef float    f32x4 __attribute__((ext_vector_type(4)));
typedef unsigned int u32x4 __attribute__((ext_vector_type(4)));

// ---------------- Mtab (fp16): M[v][c] = sum_e emb[v][e]*w_in[e][c] + b_in[c]
__global__ __launch_bounds__(256, 1) void emb_gemm(
    const float* __restrict__ emb, const float* __restrict__ w_in,
    const float* __restrict__ b_in, _Float16* __restrict__ Mtab)
{
    __shared__ float se[16][256];
    const int tid = threadIdx.x;
    const int c   = blockIdx.x * 256 + tid;   // 12 x
    const int v0  = blockIdx.y * 16;          // 8 y
#pragma unroll
    for (int i = 0; i < 16; ++i) {
        int flat = i * 256 + tid;
        int r = flat >> 8, e = flat & 255;
        se[r][e] = emb[(v0 + r) * 256 + e];
    }
    __syncthreads();
    float acc[16];
#pragma unroll
    for (int r = 0; r < 16; ++r) acc[r] = 0.f;
    for (int e = 0; e < 256; ++e) {
        float w = w_in[(size_t)e * C3N + c];
#pragma unroll
        for (int r = 0; r < 16; ++r) acc[r] = fmaf(se[r][e], w, acc[r]);
    }
    float bc = b_in[c];
#pragma unroll
    for (int r = 0; r < 16; ++r)
        Mtab[(size_t)(v0 + r) * C3N + c] = (_Float16)(acc[r] + bc);
}

// ---------------- persistent GRU over all T ---------------------------------
// comm layout (dwords): [rep][parity][plane mt][16384], rep stride 131072.
__global__ __launch_bounds__(256, 1) void gru_persist(
    const int* __restrict__ ids, const _Float16* __restrict__ Mtab_g,
    const float* __restrict__ w_rec, const float* __restrict__ b_rec,
    unsigned int* __restrict__ comm,    // NREP * 2 * 65536 dwords (1 MB)
    _Float16* __restrict__ hs)          // [T][B][H] fp16
{
    __shared__ _Float16 wh[32 * 64 * 8];      // 32 KB, B-frags [kt][lane][8]
    __shared__ _Float16 mtab[VOCABN * 48];    // 12 KB
    const half8* whp = (const half8*)wh;

    const int tid = threadIdx.x;
    const int w   = blockIdx.x;           // 0..63
    const int mt  = tid >> 6;
    const int l   = tid & 63;
    const int jj  = l & 15;
    const int lh  = l >> 4;

    // ---- LDS init: W_h in B-frag order ----------------------------------
    for (int i = 0; i < 64; ++i) {
        int flat = i * 256 + tid;                       // 16384 = 32*64*8
        int e  = flat & 7;
        int ll = (flat >> 3) & 63;
        int kt = flat >> 9;
        int k   = kt * 32 + (ll >> 4) * 8 + e;
        int col = 2048 + w * 16 + (ll & 15);
        wh[(kt * 64 + ll) * 8 + e] = (_Float16)w_rec[(size_t)k * C3N + col];
    }
    for (int i = 0; i < 24; ++i) {
        int flat = i * 256 + tid;                       // 6144 = 128*48
        int v = flat / 48, c = flat % 48;
        int col = (c >> 4) * 1024 + w * 16 + (c & 15);
        mtab[v * 48 + c] = Mtab_g[(size_t)v * C3N + col];
    }
    // ---- register(AGPR)-resident weights: z and r gates ------------------
    half8 wz[32], wr[32];
#pragma unroll
    for (int kt = 0; kt < 32; ++kt) {
#pragma unroll
        for (int e = 0; e < 8; ++e) {
            int k = kt * 32 + lh * 8 + e;
            wz[kt][e] = (_Float16)w_rec[(size_t)k * C3N + w * 16 + jj];
            wr[kt][e] = (_Float16)w_rec[(size_t)k * C3N + 1024 + w * 16 + jj];
        }
    }
    const float bz = b_rec[w * 16 + jj];
    const float br = b_rec[1024 + w * 16 + jj];
    const float bh = b_rec[2048 + w * 16 + jj];
    __syncthreads();                                    // last barrier

    const int bbase = mt * 16 + lh * 4;
    float hprev[4] = {0.f, 0.f, 0.f, 0.f};

    const int ktp = w >> 1;
    const int lp  = 16 * ((w & 1) * 2 + (jj >> 3));
    unsigned int* cw_base = comm + (size_t)mt * 16384 + ktp * 512 + lp * 8 + (jj & 7);
    const unsigned int* plane_base = comm + (size_t)(w & 1) * 131072
                                   + (size_t)mt * 16384;
    const unsigned int* cr_base = plane_base + (size_t)l * 8;

    int idsv[4];
#pragma unroll
    for (int q = 0; q < 4; ++q) idsv[q] = ids[(size_t)(bbase + q) * TN];

#define ISSUE(BUF, G) do { _Pragma("unroll")                                  \
    for (int u_ = 0; u_ < 4; ++u_) {                                          \
        asm volatile("global_load_dwordx4 %0, %1, off sc0 sc1"                \
            : "=v"(BUF[2*u_])   : "v"(crd + (4*(G)+u_)*512)     : "memory");  \
        asm volatile("global_load_dwordx4 %0, %1, off sc0 sc1"                \
            : "=v"(BUF[2*u_+1]) : "v"(crd + (4*(G)+u_)*512 + 4) : "memory");  \
    } } while (0)

#define WAITN(N) do {                                                         \
    asm volatile("s_waitcnt vmcnt(" #N ")" ::: "memory");                     \
    __builtin_amdgcn_sched_barrier(0); } while (0)

// validate chunk C (8 tagged dwords in LO/HI); stale -> reload just this
// chunk and re-check; then pack (v_perm) and 3 MFMA. C is compile-time.
#define PROC1(LO, HI, C) do {                                                 \
    u32x4 lo_ = (LO), hi_ = (HI);                                             \
    for (;;) {                                                                \
        unsigned int mv_ = lo_[0];                                            \
        mv_ = lo_[1] < mv_ ? lo_[1] : mv_;                                    \
        mv_ = lo_[2] < mv_ ? lo_[2] : mv_;                                    \
        mv_ = lo_[3] < mv_ ? lo_[3] : mv_;                                    \
        mv_ = hi_[0] < mv_ ? hi_[0] : mv_;                                    \
        mv_ = hi_[1] < mv_ ? hi_[1] : mv_;                                    \
        mv_ = hi_[2] < mv_ ? hi_[2] : mv_;                                    \
        mv_ = hi_[3] < mv_ ? hi_[3] : mv_;                                    \
        if (__all((mv_ >> 16) == tg)) break;                                  \
        asm volatile("global_load_dwordx4 %0, %1, off sc0 sc1"                \
            : "=v"(lo_) : "v"(crd + (C)*512) : "memory");                     \
        asm volatile("global_load_dwordx4 %0, %1, off sc0 sc1"                \
            : "=v"(hi_) : "v"(crd + (C)*512 + 4) : "memory");                 \
        asm volatile("s_waitcnt vmcnt(0)" ::: "memory");                      \
        __builtin_amdgcn_sched_barrier(0);                                    \
    }                                                                         \
    u32x4 fr_;                                                                \
    fr_[0] = __builtin_amdgcn_perm(lo_[1], lo_[0], 0x05040100u);              \
    fr_[1] = __builtin_amdgcn_perm(lo_[3], lo_[2], 0x05040100u);              \
    fr_[2] = __builtin_amdgcn_perm(hi_[1], hi_[0], 0x05040100u);              \
    fr_[3] = __builtin_amdgcn_perm(hi_[3], hi_[2], 0x05040100u);              \
    half8 a_ = __builtin_bit_cast(half8, fr_);                                \
    acc0 = __builtin_amdgcn_mfma_f32_16x16x32_f16(a_, wz[C], acc0, 0, 0, 0);  \
    acc1 = __builtin_amdgcn_mfma_f32_16x16x32_f16(a_, wr[C], acc1, 0, 0, 0);  \
    acc2 = __builtin_amdgcn_mfma_f32_16x16x32_f16(a_, whp[(C)*64 + l], acc2, 0, 0, 0); \
} while (0)

#define PROCG(BUF, G) do {                                                    \
    PROC1(BUF[0], BUF[1], 4*(G));                                             \
    PROC1(BUF[2], BUF[3], 4*(G)+1);                                           \
    PROC1(BUF[4], BUF[5], 4*(G)+2);                                           \
    PROC1(BUF[6], BUF[7], 4*(G)+3);                                           \
} while (0)

    for (int t = 0; t < TN; ++t) {
        f32x4 acc0 = {0.f, 0.f, 0.f, 0.f};
        f32x4 acc1 = {0.f, 0.f, 0.f, 0.f};
        f32x4 acc2 = {0.f, 0.f, 0.f, 0.f};

        if (t > 0) {
            const unsigned int tg = (unsigned int)t;
            const unsigned int* crd = cr_base + (size_t)(t & 1) * 65536;
            // probe the LAST-issued slot of producer l in my replica:
            // (lh=0,jj=0,q=3) -> +3*8 = +24 dwords past the producer base.
            const unsigned int* prp = plane_base + (size_t)(t & 1) * 65536
                                    + (l >> 1) * 512 + (l & 1) * 256 + 24;
            while (true) {
                unsigned int p;
                asm volatile("global_load_dword %0, %1, off sc0 sc1\n\t"
                             "s_waitcnt vmcnt(0)"
                             : "=v"(p) : "v"(prp) : "memory");
                if (__all((p >> 16) == tg)) break;
                __builtin_amdgcn_s_sleep(1);
            }
            __builtin_amdgcn_sched_barrier(0);

            u32x4 bufA[8], bufB[8], bufC[8], bufD[8];
            ISSUE(bufA, 0); ISSUE(bufB, 1); ISSUE(bufC, 2); ISSUE(bufD, 3);
            WAITN(24); PROCG(bufA, 0);
            ISSUE(bufA, 4);
            WAITN(24); PROCG(bufB, 1); ISSUE(bufB, 5);
            WAITN(24); PROCG(bufC, 2); ISSUE(bufC, 6);
            WAITN(24); PROCG(bufD, 3); ISSUE(bufD, 7);
            WAITN(24); PROCG(bufA, 4);
            WAITN(16); PROCG(bufB, 5);
            WAITN(8);  PROCG(bufC, 6);
            WAITN(0);  PROCG(bufD, 7);
        }

        // ---- gates (C layout: col=lane&15, row=(lane>>4)*4+q) ------------
        float hnv[4];
#pragma unroll
        for (int q = 0; q < 4; ++q) {
            float az = acc0[q], ar = acc1[q], ah = acc2[q];
            int id = idsv[q];
            float xz = (float)mtab[id * 48 + jj];
            float xr = (float)mtab[id * 48 + 16 + jj];
            float xh = (float)mtab[id * 48 + 32 + jj];
            float z  = 1.f / (1.f + __expf(-(xz + az + bz)));
            float r  = 1.f / (1.f + __expf(-(xr + ar + br)));
            float hh = tanhf(xh + r * (ah + bh));
            float hn = z * hprev[q] + (1.f - z) * hh;
            hprev[q] = hn;
            hnv[q] = hn;
        }
        // ---- publish h_{t+1}: tagged dwords, fire-and-forget -------------
        const unsigned int tagp = (unsigned int)(t + 1) << 16;
        unsigned int* cwp = cw_base + (size_t)((t + 1) & 1) * 65536;
#pragma unroll
        for (int q = 0; q < 4; ++q) {
            unsigned int hv = tagp | (unsigned int)__builtin_bit_cast(
                unsigned short, (_Float16)hnv[q]);
#pragma unroll
            for (int rr = 0; rr < NREP; ++rr)
                asm volatile("global_store_dword %0, %1, off sc0 sc1"
                             :: "v"(cwp + rr * 131072 + (lh * 4 + q) * 8),
                                "v"(hv) : "memory");
        }
        // hs stores (plain cached) + ids prefetch
#pragma unroll
        for (int q = 0; q < 4; ++q)
            hs[((size_t)t * BN + (bbase + q)) * HIDN + w * 16 + jj] = (_Float16)hnv[q];
        if (t + 1 < TN) {
#pragma unroll
            for (int q = 0; q < 4; ++q)
                idsv[q] = ids[(size_t)(bbase + q) * TN + t + 1];
        }
    }
#undef ISSUE
#undef WAITN
#undef PROC1
#undef PROCG
}

// ---------------- logits: hs[T*B,H] fp16 @ w_out + b_out --------------------
__global__ __launch_bounds__(256, 2) void out_gemm(
    const _Float16* __restrict__ hs, const float* __restrict__ w_out,
    const float* __restrict__ b_out, float* __restrict__ out)
{
    __shared__ float sa[16][1024];
    const int tid = threadIdx.x;
    const int m0  = blockIdx.x * 16;
#pragma unroll
    for (int i = 0; i < 8; ++i) {
        int flat = i * 256 + tid;
        int r = flat >> 7, kc = flat & 127;
        half8 hv = *(const half8*)(hs + (size_t)(m0 + r) * 1024 + kc * 8);
#pragma unroll
        for (int e = 0; e < 8; ++e) sa[r][kc * 8 + e] = (float)hv[e];
    }
    __syncthreads();
    const int v = tid & 127, g = tid >> 7;
    float acc[8];
#pragma unroll
    for (int r = 0; r < 8; ++r) acc[r] = 0.f;
    for (int k = 0; k < 1024; ++k) {
        float wv = w_out[(size_t)k * VOCABN + v];
#pragma unroll
        for (int r = 0; r < 8; ++r) acc[r] = fmaf(sa[g * 8 + r][k], wv, acc[r]);
    }
    float bo = b_out[v];
#pragma unroll
    for (int r = 0; r < 8; ++r) {
        int m = m0 + g * 8 + r;
        out[((size_t)(m & 63) * TN + (m >> 6)) * VOCABN + v] = acc[r] + bo;
    }
}

extern "C" void kernel_launch(void* const* d_in, const int* in_sizes, int n_in,
                              void* d_out, int out_size, void* d_ws, size_t ws_size,
                              hipStream_t stream) {
    const int*   ids   = (const int*)d_in[0];
    const float* emb   = (const float*)d_in[1];
    const float* w_in  = (const float*)d_in[2];
    const float* b_in  = (const float*)d_in[3];
    const float* w_rec = (const float*)d_in[4];
    const float* b_rec = (const float*)d_in[5];
    const float* w_out = (const float*)d_in[6];
    const float* b_out = (const float*)d_in[7];
    float* out = (float*)d_out;

    char* ws = (char*)d_ws;
    _Float16* Mtab = (_Float16*)ws;                        // 768 KB (fp16)
    size_t off = (size_t)VOCABN * C3N * 2;
    unsigned int* comm = (unsigned int*)(ws + off);
    off += (size_t)NREP * 2 * 65536 * 4;                   // 1 MB
    _Float16* hs = (_Float16*)(ws + off);                  // 128 MB

    emb_gemm<<<dim3(12, 8), 256, 0, stream>>>(emb, w_in, b_in, Mtab);
    hipMemsetAsync(comm, 0, (size_t)NREP * 2 * 65536 * 4, stream);

    gru_persist<<<NWG, 256, 0, stream>>>(ids, Mtab, w_rec, b_rec, comm, hs);
    out_gemm<<<(BN * TN) / 16, 256, 0, stream>>>(hs, w_out, b_out, out);
}

// Round 10
// 4752.551 us; speedup vs baseline: 1.9867x; 1.9314x over previous
//
#include <hip/hip_runtime.h>
#include <hip/hip_bf16.h>
#include <hip/hip_fp16.h>
#include <cstddef>

// GRU (Keras reset_after=True), persistent kernel, R6 flag protocol.
//   R10: grid 256 WGs x 64 threads -- ONE WAVE PER WG = (col-slice w, plane mt).
//   WG (w,mt): owns hidden [16w,16w+16) for batches [16mt,16mt+16).
//   Each wave gets a full CU (exclusive vmem queue + MFMA pipe, 256 CUs
//   of LLC bandwidth). 3-group load ladder = 24 chunks in flight (vs 16).
//   Protocol/layout byte-identical to R6 (best known: 5146 us):
//   per-(w,mt) flags (64B stride, x4 replicas), comm fp16 in MFMA A-frag
//   order (x4 replicas, consumer reads replica w&3), fire publish -> drain
//   vmcnt -> flag; wz/wr register(AGPR)-resident, wh in LDS.

#define VOCABN 128
#define HIDN   1024
#define BN     64
#define TN     1024
#define C3N    3072
#define NREP   4

typedef _Float16 half8 __attribute__((ext_vector_type(8)));
typedef float    f32x4 __attribute__((ext_vector_type(4)));
typedef unsigned int u32x4 __attribute__((ext_vector_type(4)));

// ---------------- Mtab (fp16): M[v][c] = sum_e emb[v][e]*w_in[e][c] + b_in[c]
__global__ __launch_bounds__(256, 1) void emb_gemm(
    const float* __restrict__ emb, const float* __restrict__ w_in,
    const float* __restrict__ b_in, _Float16* __restrict__ Mtab)
{
    __shared__ float se[16][256];
    const int tid = threadIdx.x;
    const int c   = blockIdx.x * 256 + tid;   // 12 x
    const int v0  = blockIdx.y * 16;          // 8 y
#pragma unroll
    for (int i = 0; i < 16; ++i) {
        int flat = i * 256 + tid;
        int r = flat >> 8, e = flat & 255;
        se[r][e] = emb[(v0 + r) * 256 + e];
    }
    __syncthreads();
    float acc[16];
#pragma unroll
    for (int r = 0; r < 16; ++r) acc[r] = 0.f;
    for (int e = 0; e < 256; ++e) {
        float w = w_in[(size_t)e * C3N + c];
#pragma unroll
        for (int r = 0; r < 16; ++r) acc[r] = fmaf(se[r][e], w, acc[r]);
    }
    float bc = b_in[c];
#pragma unroll
    for (int r = 0; r < 16; ++r)
        Mtab[(size_t)(v0 + r) * C3N + c] = (_Float16)(acc[r] + bc);
}

// ---------------- persistent GRU over all T ---------------------------------
// comm (halves): [rep 131072][parity 65536][plane 16384]; flags: [rep 4096 u32]
__global__ __launch_bounds__(64, 1) void gru_persist(
    const int* __restrict__ ids, const _Float16* __restrict__ Mtab_g,
    const float* __restrict__ w_rec, const float* __restrict__ b_rec,
    _Float16* __restrict__ comm,        // NREP * 2 * 65536 halves (1 MB)
    unsigned int* __restrict__ flags,   // NREP * 4096 u32 (64 KB)
    _Float16* __restrict__ hs)          // [T][B][H] fp16
{
    __shared__ _Float16 wh[32 * 64 * 8];      // 32 KB, B-frags [kt][lane][8]
    __shared__ _Float16 mtab[VOCABN * 48];    // 12 KB
    const half8* whp = (const half8*)wh;

    const int l  = threadIdx.x;          // 0..63 (one wave)
    const int w  = blockIdx.x & 63;      // column slice
    const int mt = blockIdx.x >> 6;      // plane (batch group of 16)
    const int jj = l & 15;
    const int lh = l >> 4;

    // ---- LDS init: W_h in B-frag order (64 threads) ----------------------
    for (int i = 0; i < 256; ++i) {
        int flat = i * 64 + l;                          // 16384 = 32*64*8
        int e  = flat & 7;
        int ll = (flat >> 3) & 63;
        int kt = flat >> 9;
        int k   = kt * 32 + (ll >> 4) * 8 + e;
        int col = 2048 + w * 16 + (ll & 15);
        wh[(kt * 64 + ll) * 8 + e] = (_Float16)w_rec[(size_t)k * C3N + col];
    }
    for (int i = 0; i < 96; ++i) {
        int flat = i * 64 + l;                          // 6144 = 128*48
        int v = flat / 48, c = flat % 48;
        int col = (c >> 4) * 1024 + w * 16 + (c & 15);
        mtab[v * 48 + c] = Mtab_g[(size_t)v * C3N + col];
    }
    // ---- register(AGPR)-resident weights: z and r gates ------------------
    half8 wz[32], wr[32];
#pragma unroll
    for (int kt = 0; kt < 32; ++kt) {
#pragma unroll
        for (int e = 0; e < 8; ++e) {
            int k = kt * 32 + lh * 8 + e;
            wz[kt][e] = (_Float16)w_rec[(size_t)k * C3N + w * 16 + jj];
            wr[kt][e] = (_Float16)w_rec[(size_t)k * C3N + 1024 + w * 16 + jj];
        }
    }
    const float bz = b_rec[w * 16 + jj];
    const float br = b_rec[1024 + w * 16 + jj];
    const float bh = b_rec[2048 + w * 16 + jj];
    __syncthreads();

    const int bbase = mt * 16 + lh * 4;
    float hprev[4] = {0.f, 0.f, 0.f, 0.f};

    // producer store base (A-frag coords of own h elements)
    const int ktp = w >> 1;
    const int lp  = 16 * ((w & 1) * 2 + (jj >> 3));
    _Float16* cw_base = comm + (size_t)mt * 16384 + ktp * 512 + lp * 8 + (jj & 7);
    const _Float16* cr_base = comm + (size_t)(w & 3) * 131072
                            + (size_t)mt * 16384 + (size_t)l * 8;
    unsigned int* myflag = flags + (w * 4 + mt) * 16;
    const unsigned int* pollp = flags + (w & 3) * 4096 + (l * 4 + mt) * 16;

    int idsv[4];
#pragma unroll
    for (int q = 0; q < 4; ++q) idsv[q] = ids[(size_t)(bbase + q) * TN];

#define ISSUE(BUF, G) do { _Pragma("unroll")                                  \
    for (int i_ = 0; i_ < 8; ++i_)                                            \
        asm volatile("global_load_dwordx4 %0, %1, off sc0 sc1"                \
            : "=v"(BUF[i_]) : "v"(crd + (8*(G)+i_) * 512) : "memory");        \
    } while (0)

#define WAITN(N) do {                                                         \
    asm volatile("s_waitcnt vmcnt(" #N ")" ::: "memory");                     \
    __builtin_amdgcn_sched_barrier(0); } while (0)

#define PROCG(BUF, G) do { _Pragma("unroll")                                  \
    for (int i_ = 0; i_ < 8; ++i_) {                                          \
        half8 a_ = __builtin_bit_cast(half8, BUF[i_]);                        \
        int kt_ = 8*(G) + i_;                                                 \
        acc0 = __builtin_amdgcn_mfma_f32_16x16x32_f16(a_, wz[kt_], acc0, 0, 0, 0); \
        acc1 = __builtin_amdgcn_mfma_f32_16x16x32_f16(a_, wr[kt_], acc1, 0, 0, 0); \
        acc2 = __builtin_amdgcn_mfma_f32_16x16x32_f16(a_, whp[kt_ * 64 + l], acc2, 0, 0, 0); \
    } } while (0)

    for (int t = 0; t < TN; ++t) {
        // ---- poll: 64 producer waves of my plane published h_t -----------
        {
            const unsigned int tv = (unsigned int)t;
            while (true) {
                unsigned int f;
                asm volatile("global_load_dword %0, %1, off sc0 sc1\n\t"
                             "s_waitcnt vmcnt(0)"
                             : "=v"(f) : "v"(pollp) : "memory");
                if (__all(f >= tv)) break;
                __builtin_amdgcn_s_sleep(1);
            }
        }
        __builtin_amdgcn_sched_barrier(0);

        const _Float16* crd = cr_base + (size_t)(t & 1) * 65536;
        u32x4 bA[8], bB[8], bC[8];
        f32x4 acc0 = {0.f, 0.f, 0.f, 0.f};
        f32x4 acc1 = {0.f, 0.f, 0.f, 0.f};
        f32x4 acc2 = {0.f, 0.f, 0.f, 0.f};

        ISSUE(bA, 0); ISSUE(bB, 1); ISSUE(bC, 2);       // 24 loads in flight
        WAITN(16); PROCG(bA, 0); ISSUE(bA, 3);          // chunks 24-31 -> A
        WAITN(16); PROCG(bB, 1);
        WAITN(8);  PROCG(bC, 2);
        WAITN(0);  PROCG(bA, 3);

        // ---- gates (C layout: col=lane&15, row=(lane>>4)*4+q) ------------
        float hnv[4];
#pragma unroll
        for (int q = 0; q < 4; ++q) {
            float az = acc0[q], ar = acc1[q], ah = acc2[q];
            int id = idsv[q];
            float xz = (float)mtab[id * 48 + jj];
            float xr = (float)mtab[id * 48 + 16 + jj];
            float xh = (float)mtab[id * 48 + 32 + jj];
            float z  = 1.f / (1.f + __expf(-(xz + az + bz)));
            float r  = 1.f / (1.f + __expf(-(xr + ar + br)));
            float hh = tanhf(xh + r * (ah + bh));
            float hn = z * hprev[q] + (1.f - z) * hh;
            hprev[q] = hn;
            hnv[q] = hn;
        }
        // ---- publish h_{t+1}: 2B scatter to all replicas -----------------
        _Float16* cwp = cw_base + (size_t)((t + 1) & 1) * 65536;
#pragma unroll
        for (int q = 0; q < 4; ++q) {
            unsigned int hv = (unsigned int)__builtin_bit_cast(
                unsigned short, (_Float16)hnv[q]);
#pragma unroll
            for (int rr = 0; rr < NREP; ++rr)
                asm volatile("global_store_short %0, %1, off sc0 sc1"
                             :: "v"(cwp + rr * 131072 + (lh * 4 + q) * 8),
                                "v"(hv) : "memory");
        }
        // hs stores + ids prefetch fly during the drain
#pragma unroll
        for (int q = 0; q < 4; ++q)
            hs[((size_t)t * BN + (bbase + q)) * HIDN + w * 16 + jj] = (_Float16)hnv[q];
        if (t + 1 < TN) {
#pragma unroll
            for (int q = 0; q < 4; ++q)
                idsv[q] = ids[(size_t)(bbase + q) * TN + t + 1];
        }
        WAITN(8);                                       // 16 comm stores done
        if (l == 0) {
            unsigned int fv = (unsigned int)(t + 1);
#pragma unroll
            for (int rr = 0; rr < NREP; ++rr)
                asm volatile("global_store_dword %0, %1, off sc0 sc1"
                             :: "v"(myflag + rr * 4096), "v"(fv) : "memory");
        }
    }
#undef ISSUE
#undef WAITN
#undef PROCG
}

// ---------------- logits: hs[T*B,H] fp16 @ w_out + b_out --------------------
__global__ __launch_bounds__(256, 2) void out_gemm(
    const _Float16* __restrict__ hs, const float* __restrict__ w_out,
    const float* __restrict__ b_out, float* __restrict__ out)
{
    __shared__ float sa[16][1024];
    const int tid = threadIdx.x;
    const int m0  = blockIdx.x * 16;
#pragma unroll
    for (int i = 0; i < 8; ++i) {
        int flat = i * 256 + tid;
        int r = flat >> 7, kc = flat & 127;
        half8 hv = *(const half8*)(hs + (size_t)(m0 + r) * 1024 + kc * 8);
#pragma unroll
        for (int e = 0; e < 8; ++e) sa[r][kc * 8 + e] = (float)hv[e];
    }
    __syncthreads();
    const int v = tid & 127, g = tid >> 7;
    float acc[8];
#pragma unroll
    for (int r = 0; r < 8; ++r) acc[r] = 0.f;
    for (int k = 0; k < 1024; ++k) {
        float wv = w_out[(size_t)k * VOCABN + v];
#pragma unroll
        for (int r = 0; r < 8; ++r) acc[r] = fmaf(sa[g * 8 + r][k], wv, acc[r]);
    }
    float bo = b_out[v];
#pragma unroll
    for (int r = 0; r < 8; ++r) {
        int m = m0 + g * 8 + r;
        out[((size_t)(m & 63) * TN + (m >> 6)) * VOCABN + v] = acc[r] + bo;
    }
}

extern "C" void kernel_launch(void* const* d_in, const int* in_sizes, int n_in,
                              void* d_out, int out_size, void* d_ws, size_t ws_size,
                              hipStream_t stream) {
    const int*   ids   = (const int*)d_in[0];
    const float* emb   = (const float*)d_in[1];
    const float* w_in  = (const float*)d_in[2];
    const float* b_in  = (const float*)d_in[3];
    const float* w_rec = (const float*)d_in[4];
    const float* b_rec = (const float*)d_in[5];
    const float* w_out = (const float*)d_in[6];
    const float* b_out = (const float*)d_in[7];
    float* out = (float*)d_out;

    char* ws = (char*)d_ws;
    _Float16* Mtab = (_Float16*)ws;                        // 768 KB (fp16)
    size_t off = (size_t)VOCABN * C3N * 2;
    _Float16* comm = (_Float16*)(ws + off); off += (size_t)NREP * 131072 * 2;  // 1 MB
    unsigned int* flags = (unsigned int*)(ws + off); off += NREP * 4096 * 4;   // 64 KB
    _Float16* hs = (_Float16*)(ws + off);                  // 128 MB

    emb_gemm<<<dim3(12, 8), 256, 0, stream>>>(emb, w_in, b_in, Mtab);
    hipMemsetAsync(comm, 0, (size_t)NREP * 131072 * 2, stream);
    hipMemsetAsync(flags, 0, NREP * 4096 * 4, stream);

    gru_persist<<<256, 64, 0, stream>>>(ids, Mtab, w_rec, b_rec,
                                        comm, flags, hs);
    out_gemm<<<(BN * TN) / 16, 256, 0, stream>>>(hs, w_out, b_out, out);
}

// Round 12
// 4610.867 us; speedup vs baseline: 2.0478x; 1.0307x over previous
//
#include <hip/hip_runtime.h>
#include <hip/hip_bf16.h>
#include <hip/hip_fp16.h>
#include <cstddef>

// GRU (Keras reset_after=True), persistent kernel, R10 protocol + packed publish.
//   Grid 256 WGs x 64 threads, one wave per WG = (col-slice w, plane mt).
//   R11 lesson: sc0-only (SE scope) comm is NOT coherent across an XCD's SEs
//   -> hang; device scope bypasses the non-coherent L2s. LLC (sc0 sc1) is the
//   only cross-CU coherence point. R12 deltas vs R10 (best 4368us):
//   (1) packed publish: in-wave LDS transpose (batch-major 16x16) so each
//       lane stores ONE coalesced dwordx2 -- full-line writes, kills the ~9x
//       partial-line RMW amplification (WRITE_SIZE 1212MB -> ~350MB);
//   (2) NREP 4->2 (replication measured worth only ~3% in R6).
//   Consumer side byte-identical to R10.

#define VOCABN 128
#define HIDN   1024
#define BN     64
#define TN     1024
#define C3N    3072
#define NREP   2

typedef _Float16 half8 __attribute__((ext_vector_type(8)));
typedef float    f32x4 __attribute__((ext_vector_type(4)));
typedef unsigned int u32x4 __attribute__((ext_vector_type(4)));
typedef unsigned int u32x2 __attribute__((ext_vector_type(2)));

// ---------------- Mtab (fp16): M[v][c] = sum_e emb[v][e]*w_in[e][c] + b_in[c]
__global__ __launch_bounds__(256, 1) void emb_gemm(
    const float* __restrict__ emb, const float* __restrict__ w_in,
    const float* __restrict__ b_in, _Float16* __restrict__ Mtab)
{
    __shared__ float se[16][256];
    const int tid = threadIdx.x;
    const int c   = blockIdx.x * 256 + tid;   // 12 x
    const int v0  = blockIdx.y * 16;          // 8 y
#pragma unroll
    for (int i = 0; i < 16; ++i) {
        int flat = i * 256 + tid;
        int r = flat >> 8, e = flat & 255;
        se[r][e] = emb[(v0 + r) * 256 + e];
    }
    __syncthreads();
    float acc[16];
#pragma unroll
    for (int r = 0; r < 16; ++r) acc[r] = 0.f;
    for (int e = 0; e < 256; ++e) {
        float w = w_in[(size_t)e * C3N + c];
#pragma unroll
        for (int r = 0; r < 16; ++r) acc[r] = fmaf(se[r][e], w, acc[r]);
    }
    float bc = b_in[c];
#pragma unroll
    for (int r = 0; r < 16; ++r)
        Mtab[(size_t)(v0 + r) * C3N + c] = (_Float16)(acc[r] + bc);
}

// ---------------- persistent GRU over all T ---------------------------------
// comm (halves): [rep 131072][parity 65536][plane 16384]; flags: [rep 4096 u32]
__global__ __launch_bounds__(64, 1) void gru_persist(
    const int* __restrict__ ids, const _Float16* __restrict__ Mtab_g,
    const float* __restrict__ w_rec, const float* __restrict__ b_rec,
    _Float16* __restrict__ comm,        // NREP * 2 * 65536 halves (512 KB)
    unsigned int* __restrict__ flags,   // NREP * 4096 u32 (32 KB)
    _Float16* __restrict__ hs)          // [T][B][H] fp16
{
    __shared__ _Float16 wh[32 * 64 * 8];      // 32 KB, B-frags [kt][lane][8]
    __shared__ _Float16 mtab[VOCABN * 48];    // 12 KB
    __shared__ __align__(16) _Float16 sht[256];  // 512 B transpose buffer
    const half8* whp = (const half8*)wh;

    const int l  = threadIdx.x;          // 0..63 (one wave)
    const int w  = blockIdx.x & 63;      // column slice
    const int mt = blockIdx.x >> 6;      // plane (batch group of 16)
    const int jj = l & 15;
    const int lh = l >> 4;

    // ---- LDS init: W_h in B-frag order (64 threads) ----------------------
    for (int i = 0; i < 256; ++i) {
        int flat = i * 64 + l;                          // 16384 = 32*64*8
        int e  = flat & 7;
        int ll = (flat >> 3) & 63;
        int kt = flat >> 9;
        int k   = kt * 32 + (ll >> 4) * 8 + e;
        int col = 2048 + w * 16 + (ll & 15);
        wh[(kt * 64 + ll) * 8 + e] = (_Float16)w_rec[(size_t)k * C3N + col];
    }
    for (int i = 0; i < 96; ++i) {
        int flat = i * 64 + l;                          // 6144 = 128*48
        int v = flat / 48, c = flat % 48;
        int col = (c >> 4) * 1024 + w * 16 + (c & 15);
        mtab[v * 48 + c] = Mtab_g[(size_t)v * C3N + col];
    }
    // ---- register(AGPR)-resident weights: z and r gates ------------------
    half8 wz[32], wr[32];
#pragma unroll
    for (int kt = 0; kt < 32; ++kt) {
#pragma unroll
        for (int e = 0; e < 8; ++e) {
            int k = kt * 32 + lh * 8 + e;
            wz[kt][e] = (_Float16)w_rec[(size_t)k * C3N + w * 16 + jj];
            wr[kt][e] = (_Float16)w_rec[(size_t)k * C3N + 1024 + w * 16 + jj];
        }
    }
    const float bz = b_rec[w * 16 + jj];
    const float br = b_rec[1024 + w * 16 + jj];
    const float bh = b_rec[2048 + w * 16 + jj];
    __syncthreads();

    const int bbase = mt * 16 + lh * 4;
    float hprev[4] = {0.f, 0.f, 0.f, 0.f};

    // packed-publish base: half-offset = ktp*512 + (w&1)*256 + l*4
    const int ktp = w >> 1;
    _Float16* cw_base = comm + (size_t)mt * 16384 + ktp * 512
                      + (w & 1) * 256 + l * 4;
    const _Float16* cr_base = comm + (size_t)(w & 1) * 131072
                            + (size_t)mt * 16384 + (size_t)l * 8;
    unsigned int* myflag = flags + (w * 4 + mt) * 16;
    const unsigned int* pollp = flags + (w & 1) * 4096 + (l * 4 + mt) * 16;

    int idsv[4];
#pragma unroll
    for (int q = 0; q < 4; ++q) idsv[q] = ids[(size_t)(bbase + q) * TN];

#define ISSUE(BUF, G) do { _Pragma("unroll")                                  \
    for (int i_ = 0; i_ < 8; ++i_)                                            \
        asm volatile("global_load_dwordx4 %0, %1, off sc0 sc1"                \
            : "=v"(BUF[i_]) : "v"(crd + (8*(G)+i_) * 512) : "memory");        \
    } while (0)

#define WAITN(N) do {                                                         \
    asm volatile("s_waitcnt vmcnt(" #N ")" ::: "memory");                     \
    __builtin_amdgcn_sched_barrier(0); } while (0)

#define PROCG(BUF, G) do { _Pragma("unroll")                                  \
    for (int i_ = 0; i_ < 8; ++i_) {                                          \
        half8 a_ = __builtin_bit_cast(half8, BUF[i_]);                        \
        int kt_ = 8*(G) + i_;                                                 \
        acc0 = __builtin_amdgcn_mfma_f32_16x16x32_f16(a_, wz[kt_], acc0, 0, 0, 0); \
        acc1 = __builtin_amdgcn_mfma_f32_16x16x32_f16(a_, wr[kt_], acc1, 0, 0, 0); \
        acc2 = __builtin_amdgcn_mfma_f32_16x16x32_f16(a_, whp[kt_ * 64 + l], acc2, 0, 0, 0); \
    } } while (0)

    for (int t = 0; t < TN; ++t) {
        // ---- poll: 64 producer waves of my plane published h_t -----------
        {
            const unsigned int tv = (unsigned int)t;
            while (true) {
                unsigned int f;
                asm volatile("global_load_dword %0, %1, off sc0 sc1\n\t"
                             "s_waitcnt vmcnt(0)"
                             : "=v"(f) : "v"(pollp) : "memory");
                if (__all(f >= tv)) break;
                __builtin_amdgcn_s_sleep(1);
            }
        }
        __builtin_amdgcn_sched_barrier(0);

        const _Float16* crd = cr_base + (size_t)(t & 1) * 65536;
        u32x4 bA[8], bB[8], bC[8];
        f32x4 acc0 = {0.f, 0.f, 0.f, 0.f};
        f32x4 acc1 = {0.f, 0.f, 0.f, 0.f};
        f32x4 acc2 = {0.f, 0.f, 0.f, 0.f};

        ISSUE(bA, 0); ISSUE(bB, 1); ISSUE(bC, 2);       // 24 loads in flight
        WAITN(16); PROCG(bA, 0); ISSUE(bA, 3);          // chunks 24-31 -> A
        WAITN(16); PROCG(bB, 1);
        WAITN(8);  PROCG(bC, 2);
        WAITN(0);  PROCG(bA, 3);

        // ---- gates (C layout: col=lane&15, row=(lane>>4)*4+q) ------------
        float hnv[4];
#pragma unroll
        for (int q = 0; q < 4; ++q) {
            float az = acc0[q], ar = acc1[q], ah = acc2[q];
            int id = idsv[q];
            float xz = (float)mtab[id * 48 + jj];
            float xr = (float)mtab[id * 48 + 16 + jj];
            float xh = (float)mtab[id * 48 + 32 + jj];
            float z  = 1.f / (1.f + __expf(-(xz + az + bz)));
            float r  = 1.f / (1.f + __expf(-(xr + ar + br)));
            float hh = tanhf(xh + r * (ah + bh));
            float hn = z * hprev[q] + (1.f - z) * hh;
            hprev[q] = hn;
            hnv[q] = hn;
        }
        // ---- packed publish: LDS transpose -> 1 coalesced 8B store/replica
        // write batch-major: sht[(batch%16)][jj]
#pragma unroll
        for (int q = 0; q < 4; ++q)
            sht[(lh * 4 + q) * 16 + jj] = (_Float16)hnv[q];
        asm volatile("s_waitcnt lgkmcnt(0)" ::: "memory");
        __builtin_amdgcn_sched_barrier(0);
        {
            const int B   = (l >> 1) & 15;              // batch%16 served
            const int jj0 = 8 * (l >> 5) + (l & 1) * 4; // 4 consecutive jj
            u32x2 pk = *(const u32x2*)&sht[B * 16 + jj0];
            _Float16* cwp = cw_base + (size_t)((t + 1) & 1) * 65536;
#pragma unroll
            for (int rr = 0; rr < NREP; ++rr)
                asm volatile("global_store_dwordx2 %0, %1, off sc0 sc1"
                             :: "v"(cwp + rr * 131072), "v"(pk) : "memory");
        }
        // hs stores + ids prefetch fly during the drain
#pragma unroll
        for (int q = 0; q < 4; ++q)
            hs[((size_t)t * BN + (bbase + q)) * HIDN + w * 16 + jj] = (_Float16)hnv[q];
        if (t + 1 < TN) {
#pragma unroll
            for (int q = 0; q < 4; ++q)
                idsv[q] = ids[(size_t)(bbase + q) * TN + t + 1];
        }
        WAITN(8);                                       // 2 comm stores acked
        if (l == 0) {
            unsigned int fv = (unsigned int)(t + 1);
#pragma unroll
            for (int rr = 0; rr < NREP; ++rr)
                asm volatile("global_store_dword %0, %1, off sc0 sc1"
                             :: "v"(myflag + rr * 4096), "v"(fv) : "memory");
        }
    }
#undef ISSUE
#undef WAITN
#undef PROCG
}

// ---------------- logits: hs[T*B,H] fp16 @ w_out + b_out --------------------
__global__ __launch_bounds__(256, 2) void out_gemm(
    const _Float16* __restrict__ hs, const float* __restrict__ w_out,
    const float* __restrict__ b_out, float* __restrict__ out)
{
    __shared__ float sa[16][1024];
    const int tid = threadIdx.x;
    const int m0  = blockIdx.x * 16;
#pragma unroll
    for (int i = 0; i < 8; ++i) {
        int flat = i * 256 + tid;
        int r = flat >> 7, kc = flat & 127;
        half8 hv = *(const half8*)(hs + (size_t)(m0 + r) * 1024 + kc * 8);
#pragma unroll
        for (int e = 0; e < 8; ++e) sa[r][kc * 8 + e] = (float)hv[e];
    }
    __syncthreads();
    const int v = tid & 127, g = tid >> 7;
    float acc[8];
#pragma unroll
    for (int r = 0; r < 8; ++r) acc[r] = 0.f;
    for (int k = 0; k < 1024; ++k) {
        float wv = w_out[(size_t)k * VOCABN + v];
#pragma unroll
        for (int r = 0; r < 8; ++r) acc[r] = fmaf(sa[g * 8 + r][k], wv, acc[r]);
    }
    float bo = b_out[v];
#pragma unroll
    for (int r = 0; r < 8; ++r) {
        int m = m0 + g * 8 + r;
        out[((size_t)(m & 63) * TN + (m >> 6)) * VOCABN + v] = acc[r] + bo;
    }
}

extern "C" void kernel_launch(void* const* d_in, const int* in_sizes, int n_in,
                              void* d_out, int out_size, void* d_ws, size_t ws_size,
                              hipStream_t stream) {
    const int*   ids   = (const int*)d_in[0];
    const float* emb   = (const float*)d_in[1];
    const float* w_in  = (const float*)d_in[2];
    const float* b_in  = (const float*)d_in[3];
    const float* w_rec = (const float*)d_in[4];
    const float* b_rec = (const float*)d_in[5];
    const float* w_out = (const float*)d_in[6];
    const float* b_out = (const float*)d_in[7];
    float* out = (float*)d_out;

    char* ws = (char*)d_ws;
    _Float16* Mtab = (_Float16*)ws;                        // 768 KB (fp16)
    size_t off = (size_t)VOCABN * C3N * 2;
    _Float16* comm = (_Float16*)(ws + off); off += (size_t)NREP * 131072 * 2;  // 512 KB
    unsigned int* flags = (unsigned int*)(ws + off); off += NREP * 4096 * 4;   // 32 KB
    _Float16* hs = (_Float16*)(ws + off);                  // 128 MB

    emb_gemm<<<dim3(12, 8), 256, 0, stream>>>(emb, w_in, b_in, Mtab);
    hipMemsetAsync(comm, 0, (size_t)NREP * 131072 * 2, stream);
    hipMemsetAsync(flags, 0, NREP * 4096 * 4, stream);

    gru_persist<<<256, 64, 0, stream>>>(ids, Mtab, w_rec, b_rec,
                                        comm, flags, hs);
    out_gemm<<<(BN * TN) / 16, 256, 0, stream>>>(hs, w_out, b_out, out);
}